// Round 3
// baseline (370.304 us; speedup 1.0000x reference)
//
#include <hip/hip_runtime.h>
#include <hip/hip_bf16.h>

// Implicit-GEMM conv2d 3x3 VALID, stride 1, via bf16 MFMA — fused conversion.
// x: (32,64,112,112) f32  w: (128,64,3,3) f32  bias: (128)  out: (32,128,110,110) f32
// GEMM view: M=Cout=128, K=(kh,kw,ci)=576, N=pixels. Per block: one (n,oh) row,
// tile 128co x 128px (110 valid). Staging reads x NCHW f32 directly and converts
// to bf16 NHWC-in-LDS (no xhwc pre-pass kernel, no 102 MB of layout traffic).
// K-loop has NO barriers: A frags from L2 (prepacked weights), B frags from LDS.

#define CIN   64
#define COUT  128
#define INH   112
#define INW   112
#define OUTH  110
#define OUTW  110
#define NB    32
#define KTOT  576           // k = (kh*3+kw)*64 + ci
#define NPIX  (NB*OUTH*OUTW)

typedef __attribute__((ext_vector_type(8))) short short8;     // 8 bf16 (4 VGPRs)
typedef __attribute__((ext_vector_type(4))) float f32x4;

static __device__ __forceinline__ unsigned short f2bf(float f) {
    union { float f; unsigned int u; } v; v.f = f;
    return (unsigned short)((v.u + 0x7FFF + ((v.u >> 16) & 1)) >> 16);  // RNE
}

// ---------- pre-pass: weights -> bf16, fragment-major A_packed ----------
// A_packed halfword index: ((k>>3)*128 + m)*8 + (k&7), k=(kh*3+kw)*64+ci
__global__ __launch_bounds__(256) void prepack_w(const float* __restrict__ w,
                                                 unsigned short* __restrict__ ap) {
    int flat = blockIdx.x * 256 + threadIdx.x;    // 128*576 = 73728 exactly
    int m = flat / KTOT;
    int k = flat - m * KTOT;
    int khw = k >> 6, ci = k & 63;
    int kh = khw / 3, kw = khw - kh * 3;
    float v = w[((m * CIN + ci) * 3 + kh) * 3 + kw];
    ap[((k >> 3) * COUT + m) * 8 + (k & 7)] = f2bf(v);
}

// ---------- main GEMM (fused x-conversion in staging) ----------
__global__ __launch_bounds__(256, 3) void conv_gemm(const float* __restrict__ x,
                                                    const unsigned short* __restrict__ ap,
                                                    const float* __restrict__ bias,
                                                    float* __restrict__ out) {
    // B tile: 3 input rows (oh..oh+2), per-w cell padded 64->72 halfwords
    // (b128 read lane stride 144B -> 2-way bank aliasing = free).
    // +slack so garbage-column frag reads (ow>=110) never go OOB.
    __shared__ unsigned short ldsB[25600];        // 51.2 KB -> 3 blocks/CU

    // Bijective XCD swizzle (3520 blocks = 8 x 440): adjacent-oh blocks of the
    // same n (sharing 2 of 3 x rows) land on the same XCD's L2.
    const int flat0 = blockIdx.y * OUTH + blockIdx.x;
    const int flat  = (flat0 & 7) * 440 + (flat0 >> 3);
    const int n  = flat / OUTH;
    const int oh = flat - n * OUTH;
    const int t  = threadIdx.x;

    const int lane = t & 63;
    const int wave = t >> 6;
    const int m_base  = (wave >> 1) * 64;          // co half
    const int px_base = (wave & 1) * 64;           // px half
    const int l16  = lane & 15;
    const int quad = lane >> 4;                    // 0..3

    const short8* A = (const short8*)ap;           // index kb*128 + m

    auto loadA = [&](short8* a, int kc) {
#pragma unroll
        for (int i = 0; i < 4; ++i)                // lane k-run = k&7 contiguous
            a[i] = A[(kc * 4 + quad) * COUT + (m_base + i * 16 + l16)];
    };
    auto loadB = [&](short8* b, int kc) {
        const int khw = kc >> 1;
        const int kh = khw / 3, kw = khw - kh * 3; // compile-time after unroll
        const int ci0 = (kc & 1) * 32 + quad * 8;
#pragma unroll
        for (int j = 0; j < 4; ++j) {              // 8 consecutive ci = b128
            int ow = px_base + j * 16 + l16;
            b[j] = *(const short8*)&ldsB[(kh * INW + ow + kw) * 72 + ci0];
        }
    };

    short8 a0[4], a1[4], b0[4], b1[4];
    loadA(a0, 0);                                  // L2 latency hides under staging

    {   // stage B: rows oh..oh+2 of x (NCHW f32) -> bf16 NHWC cells in LDS.
        // Per iter: float2 over w for ci and ci+1, pack 2 dwords, 2x ds_write_b32.
        // LDS write lane stride 144B (8-way bank alias) — 42 writes/thread, once
        // per block: ~130 cy/wave, negligible vs ~14K cy of MFMA.
        const float* xb = x + ((size_t)n * CIN) * (INH * INW) + (size_t)oh * INW;
        for (int c = t; c < 5376; c += 256) {      // 3r x 32cip x 56w2, 21 iters
            int w2 = c % 56;
            int rest = c / 56;                     // 0..95
            int cip = rest & 31, r = rest >> 5;
            const float* p = xb + (size_t)(2 * cip) * (INH * INW) + r * INW + 2 * w2;
            float2 va = *(const float2*)p;
            float2 vb = *(const float2*)(p + INH * INW);
            unsigned int d0 = (unsigned int)f2bf(va.x) | ((unsigned int)f2bf(vb.x) << 16);
            unsigned int d1 = (unsigned int)f2bf(va.y) | ((unsigned int)f2bf(vb.y) << 16);
            int cell = r * INW + 2 * w2;
            *(unsigned int*)&ldsB[cell * 72 + 2 * cip] = d0;
            *(unsigned int*)&ldsB[(cell + 1) * 72 + 2 * cip] = d1;
        }
    }
    loadA(a1, 1);
    __syncthreads();   // the ONLY barrier

    f32x4 acc[4][4] = {};                          // [m-tile][n-tile]
    loadB(b0, 0);
    loadB(b1, 1);

#pragma unroll
    for (int kc = 0; kc < 18; kc += 2) {
#pragma unroll
        for (int i = 0; i < 4; ++i)
#pragma unroll
            for (int j = 0; j < 4; ++j)
                acc[i][j] = __builtin_amdgcn_mfma_f32_16x16x32_bf16(a0[i], b0[j], acc[i][j], 0, 0, 0);
        if (kc + 2 < 18) { loadA(a0, kc + 2); loadB(b0, kc + 2); }
#pragma unroll
        for (int i = 0; i < 4; ++i)
#pragma unroll
            for (int j = 0; j < 4; ++j)
                acc[i][j] = __builtin_amdgcn_mfma_f32_16x16x32_bf16(a1[i], b1[j], acc[i][j], 0, 0, 0);
        if (kc + 3 < 18) { loadA(a1, kc + 3); loadB(b1, kc + 3); }
    }

    // C/D layout (verified m89): col = lane&15 -> ow, row = quad*4 + reg -> co
#pragma unroll
    for (int i = 0; i < 4; ++i) {
        const int co = m_base + i * 16 + quad * 4;
#pragma unroll
        for (int j = 0; j < 4; ++j) {
            const int ow = px_base + j * 16 + l16;
            if (ow < OUTW) {
                const size_t ob = (((size_t)n * COUT + co) * OUTH + oh) * OUTW + ow;
#pragma unroll
                for (int r = 0; r < 4; ++r)
                    out[ob + (size_t)r * (OUTH * OUTW)] = acc[i][j][r] + bias[co + r];
            }
        }
    }
}

// ---------- fallback (round-1 direct conv) if ws too small ----------
#define TCO 16
__global__ __launch_bounds__(256) void conv_direct(const float* __restrict__ x,
                                                   const float* __restrict__ w,
                                                   const float* __restrict__ bias,
                                                   float* __restrict__ out) {
    int p = blockIdx.x * 256 + threadIdx.x;
    const int co0 = blockIdx.y * TCO;
    const bool valid = p < NPIX;
    if (!valid) p = 0;
    const int n = p / (OUTH * OUTW);
    const int rem = p - n * (OUTH * OUTW);
    const int oh = rem / OUTW;
    const int ow = rem - oh * OUTW;
    float acc[TCO];
#pragma unroll
    for (int t = 0; t < TCO; ++t) acc[t] = bias[co0 + t];
    const float* xb = x + ((size_t)n * CIN) * (INH * INW) + (size_t)oh * INW + ow;
    const float* wb = w + (size_t)co0 * CIN * 9;
    for (int ci = 0; ci < CIN; ++ci) {
        const float* xp = xb + (size_t)ci * (INH * INW);
        const float* wp = wb + ci * 9;
#pragma unroll
        for (int kh = 0; kh < 3; ++kh) {
            const float x0 = xp[kh * INW + 0];
            const float x1 = xp[kh * INW + 1];
            const float x2 = xp[kh * INW + 2];
#pragma unroll
            for (int t = 0; t < TCO; ++t) {
                const float* wt = wp + t * (CIN * 9) + kh * 3;
                acc[t] = fmaf(x0, wt[0], acc[t]);
                acc[t] = fmaf(x1, wt[1], acc[t]);
                acc[t] = fmaf(x2, wt[2], acc[t]);
            }
        }
    }
    if (valid) {
        const size_t ob = ((size_t)n * COUT + co0) * (OUTH * OUTW) + (size_t)oh * OUTW + ow;
#pragma unroll
        for (int t = 0; t < TCO; ++t)
            out[ob + (size_t)t * (OUTH * OUTW)] = acc[t];
    }
}

extern "C" void kernel_launch(void* const* d_in, const int* in_sizes, int n_in,
                              void* d_out, int out_size, void* d_ws, size_t ws_size,
                              hipStream_t stream) {
    const float* x    = (const float*)d_in[0];
    const float* w    = (const float*)d_in[1];
    const float* bias = (const float*)d_in[2];
    float* out        = (float*)d_out;

    const size_t ap_bytes = (size_t)COUT * KTOT * 2;             // 147,456

    if (ws_size >= ap_bytes) {
        unsigned short* apck = (unsigned short*)d_ws;
        prepack_w<<<288, 256, 0, stream>>>(w, apck);
        conv_gemm<<<dim3(OUTH, NB), 256, 0, stream>>>(x, apck, bias, out);
    } else {
        dim3 grid((NPIX + 255) / 256, COUT / TCO);
        conv_direct<<<grid, dim3(256), 0, stream>>>(x, w, bias, out);
    }
}

// Round 4
// 324.888 us; speedup vs baseline: 1.1398x; 1.1398x over previous
//
#include <hip/hip_runtime.h>

// Implicit-GEMM conv2d 3x3 VALID, stride 1, via bf16 MFMA — fused conversion, fat waves.
// x: (32,64,112,112) f32  w: (128,64,3,3) f32  bias: (128)  out: (32,128,110,110) f32
// GEMM view: M=Cout=128, K=576, N=pixels. Per block: one n, TWO output rows (oh0,oh0+1),
// tile 128co x 256px. Per wave: 64co x 128px -> 32-MFMA runs per K-chunk (620 cy) hide
// all load latency; A dbuf from L2, B half-buffers from LDS. Staging converts x NCHW f32
// -> bf16 NHWC-in-LDS with conflict-free dword writes (bank = 4*(cell&7)+cip perm).

#define CIN   64
#define COUT  128
#define INH   112
#define INW   112
#define HW    (INH*INW)
#define OUTH  110
#define OUTW  110
#define NB    32
#define KTOT  576           // k = (kh*3+kw)*64 + ci
#define NPIX  (NB*OUTH*OUTW)

typedef __attribute__((ext_vector_type(8))) short short8;     // 8 bf16 (4 VGPRs)
typedef __attribute__((ext_vector_type(4))) float f32x4;

static __device__ __forceinline__ unsigned short f2bf(float f) {
    union { float f; unsigned int u; } v; v.f = f;
    return (unsigned short)((v.u + 0x7FFF + ((v.u >> 16) & 1)) >> 16);  // RNE
}

// ---------- pre-pass: weights -> bf16, fragment-major A_packed ----------
// A_packed halfword index: ((k>>3)*128 + m)*8 + (k&7), k=(kh*3+kw)*64+ci
__global__ __launch_bounds__(256) void prepack_w(const float* __restrict__ w,
                                                 unsigned short* __restrict__ ap) {
    int flat = blockIdx.x * 256 + threadIdx.x;    // 128*576 = 73728 exactly
    int m = flat / KTOT;
    int k = flat - m * KTOT;
    int khw = k >> 6, ci = k & 63;
    int kh = khw / 3, kw = khw - kh * 3;
    float v = w[((m * CIN + ci) * 3 + kh) * 3 + kw];
    ap[((k >> 3) * COUT + m) * 8 + (k & 7)] = f2bf(v);
}

// ---------- main GEMM (fused x-conversion, 2 output rows per block) ----------
__global__ __launch_bounds__(256, 2) void conv_gemm(const float* __restrict__ x,
                                                    const unsigned short* __restrict__ ap,
                                                    const float* __restrict__ bias,
                                                    float* __restrict__ out) {
    // B tile: 4 input rows (oh0..oh0+3), 448 cells x 72 halfwords (pitch 72 ->
    // b128 read lane stride 144B = 2-way bank alias = free). 63 KB -> 2 blocks/CU.
    __shared__ unsigned short ldsB[32256];

    // Bijective XCD swizzle (1760 blocks = 8 x 220): same-n adjacent row-pairs
    // (sharing input rows) land on the same XCD's L2.
    const int flat0 = blockIdx.y * 55 + blockIdx.x;
    const int flat  = (flat0 & 7) * 220 + (flat0 >> 3);
    const int n   = flat / 55;
    const int ohp = flat - n * 55;
    const int oh0 = ohp * 2;
    const int t   = threadIdx.x;

    const int lane = t & 63;
    const int wv   = t >> 6;
    const int m_base  = (wv >> 1) * 64;            // co half
    const int px_base = (wv & 1) * 128;            // px half (128 px = 2 orow x 64.. packed)
    const int l16  = lane & 15;
    const int quad = lane >> 4;                    // 0..3

    const short8* A = (const short8*)ap;           // index kb*128 + m

    auto loadA = [&](short8* a, int kc) {
#pragma unroll
        for (int i = 0; i < 4; ++i)                // lane k-run = k&7 contiguous
            a[i] = A[(kc * 4 + quad) * COUT + (m_base + i * 16 + l16)];
    };
    // h = 0: j 0..3, h = 1: j 4..7.  px = px_base + j*16 + l16 (never crosses 128-bdry)
    auto loadBh = [&](short8* b, int kc, int h) {
        const int khw = kc >> 1;
        const int kh = khw / 3, kw = khw - kh * 3; // compile-time after unroll
        const int ci0 = (kc & 1) * 32 + quad * 8;
#pragma unroll
        for (int jj = 0; jj < 4; ++jj) {
            int px = px_base + (h * 4 + jj) * 16 + l16;
            int orow = px >> 7;
            int ow = px & 127;
            ow = (ow < OUTW) ? ow : (OUTW - 1);    // clamp garbage cols: stay in 448 cells
            b[jj] = *(const short8*)&ldsB[((orow + kh) * INW + ow + kw) * 72 + ci0];
        }
    };

    short8 a0[4], a1[4], bA[4], bB[4];
    loadA(a0, 0);                                  // L2 latency hides under staging

    {   // stage: 4 rows x 112 w x 64 ci of x (NCHW f32) -> bf16 NHWC cells in LDS.
        // Lane map: cell = 8i + (l&7), cip = wv*8 + ((l>>3)&3) + 4*(l>>5).
        // Write bank = (4*(cell&7) + cip) mod 32 -> exactly 2 lanes/bank = free.
        // Global: 8 lanes share cip -> consecutive w -> 32B coalesced runs.
        const int cq  = lane & 7;
        const int cip = wv * 8 + ((lane >> 3) & 3) + 4 * (lane >> 5);
        const float* p0 = x + ((size_t)n * CIN + 2 * cip) * HW + (size_t)oh0 * INW;
        unsigned int* ldsW = (unsigned int*)ldsB;
#pragma unroll 8
        for (int i = 0; i < 56; ++i) {
            int cell = i * 8 + cq;                 // 0..447
            int r = cell / 112, w = cell - r * 112;
            float va = p0[r * INW + w];
            float vb = p0[HW + r * INW + w];
            ldsW[cell * 36 + cip] = (unsigned int)f2bf(va) | ((unsigned int)f2bf(vb) << 16);
        }
    }
    loadA(a1, 1);
    __syncthreads();   // the ONLY barrier

    f32x4 acc[4][8] = {};                          // [m-tile][px-tile], 128 AGPR
    loadBh(bA, 0, 0);

#pragma unroll
    for (int kc = 0; kc < 18; kc += 2) {
        // ---- even kc: A = a0 ----
        loadBh(bB, kc, 1);
        __builtin_amdgcn_s_setprio(1);
#pragma unroll
        for (int i = 0; i < 4; ++i)
#pragma unroll
            for (int jj = 0; jj < 4; ++jj)
                acc[i][jj] = __builtin_amdgcn_mfma_f32_16x16x32_bf16(a0[i], bA[jj], acc[i][jj], 0, 0, 0);
        __builtin_amdgcn_s_setprio(0);
        loadBh(bA, kc + 1, 0);                     // bA free; used 16 MFMAs from now
        __builtin_amdgcn_s_setprio(1);
#pragma unroll
        for (int i = 0; i < 4; ++i)
#pragma unroll
            for (int jj = 0; jj < 4; ++jj)
                acc[i][4 + jj] = __builtin_amdgcn_mfma_f32_16x16x32_bf16(a0[i], bB[jj], acc[i][4 + jj], 0, 0, 0);
        __builtin_amdgcn_s_setprio(0);
        if (kc + 2 < 18) loadA(a0, kc + 2);        // a0 free; full kc+1 (~620cy) to land

        // ---- odd kc+1: A = a1 ----
        loadBh(bB, kc + 1, 1);
        __builtin_amdgcn_s_setprio(1);
#pragma unroll
        for (int i = 0; i < 4; ++i)
#pragma unroll
            for (int jj = 0; jj < 4; ++jj)
                acc[i][jj] = __builtin_amdgcn_mfma_f32_16x16x32_bf16(a1[i], bA[jj], acc[i][jj], 0, 0, 0);
        __builtin_amdgcn_s_setprio(0);
        if (kc + 2 < 18) loadBh(bA, kc + 2, 0);
        __builtin_amdgcn_s_setprio(1);
#pragma unroll
        for (int i = 0; i < 4; ++i)
#pragma unroll
            for (int jj = 0; jj < 4; ++jj)
                acc[i][4 + jj] = __builtin_amdgcn_mfma_f32_16x16x32_bf16(a1[i], bB[jj], acc[i][4 + jj], 0, 0, 0);
        __builtin_amdgcn_s_setprio(0);
        if (kc + 3 < 18) loadA(a1, kc + 3);
    }

    // C/D layout (verified m89): col = lane&15 -> px, row = quad*4 + reg -> co
#pragma unroll
    for (int i = 0; i < 4; ++i) {
        const int co = m_base + i * 16 + quad * 4;
#pragma unroll
        for (int j = 0; j < 8; ++j) {
            const int px = px_base + j * 16 + l16;
            const int orow = px >> 7;
            const int ow = px & 127;
            if (ow < OUTW) {
                const size_t ob = (((size_t)n * COUT + co) * OUTH + (oh0 + orow)) * OUTW + ow;
#pragma unroll
                for (int r = 0; r < 4; ++r)
                    out[ob + (size_t)r * (OUTH * OUTW)] = acc[i][j][r] + bias[co + r];
            }
        }
    }
}

// ---------- fallback (round-1 direct conv) if ws too small ----------
#define TCO 16
__global__ __launch_bounds__(256) void conv_direct(const float* __restrict__ x,
                                                   const float* __restrict__ w,
                                                   const float* __restrict__ bias,
                                                   float* __restrict__ out) {
    int p = blockIdx.x * 256 + threadIdx.x;
    const int co0 = blockIdx.y * TCO;
    const bool valid = p < NPIX;
    if (!valid) p = 0;
    const int n = p / (OUTH * OUTW);
    const int rem = p - n * (OUTH * OUTW);
    const int oh = rem / OUTW;
    const int ow = rem - oh * OUTW;
    float acc[TCO];
#pragma unroll
    for (int t = 0; t < TCO; ++t) acc[t] = bias[co0 + t];
    const float* xb = x + ((size_t)n * CIN) * HW + (size_t)oh * INW + ow;
    const float* wb = w + (size_t)co0 * CIN * 9;
    for (int ci = 0; ci < CIN; ++ci) {
        const float* xp = xb + (size_t)ci * HW;
        const float* wp = wb + ci * 9;
#pragma unroll
        for (int kh = 0; kh < 3; ++kh) {
            const float x0 = xp[kh * INW + 0];
            const float x1 = xp[kh * INW + 1];
            const float x2 = xp[kh * INW + 2];
#pragma unroll
            for (int t = 0; t < TCO; ++t) {
                const float* wt = wp + t * (CIN * 9) + kh * 3;
                acc[t] = fmaf(x0, wt[0], acc[t]);
                acc[t] = fmaf(x1, wt[1], acc[t]);
                acc[t] = fmaf(x2, wt[2], acc[t]);
            }
        }
    }
    if (valid) {
        const size_t ob = ((size_t)n * COUT + co0) * (OUTH * OUTW) + (size_t)oh * OUTW + ow;
#pragma unroll
        for (int t = 0; t < TCO; ++t)
            out[ob + (size_t)t * (OUTH * OUTW)] = acc[t];
    }
}

extern "C" void kernel_launch(void* const* d_in, const int* in_sizes, int n_in,
                              void* d_out, int out_size, void* d_ws, size_t ws_size,
                              hipStream_t stream) {
    const float* x    = (const float*)d_in[0];
    const float* w    = (const float*)d_in[1];
    const float* bias = (const float*)d_in[2];
    float* out        = (float*)d_out;

    const size_t ap_bytes = (size_t)COUT * KTOT * 2;             // 147,456

    if (ws_size >= ap_bytes) {
        unsigned short* apck = (unsigned short*)d_ws;
        prepack_w<<<288, 256, 0, stream>>>(w, apck);
        conv_gemm<<<dim3(55, NB), 256, 0, stream>>>(x, apck, bias, out);
    } else {
        dim3 grid((NPIX + 255) / 256, COUT / TCO);
        conv_direct<<<grid, dim3(256), 0, stream>>>(x, w, bias, out);
    }
}